// Round 1
// baseline (499.348 us; speedup 1.0000x reference)
//
#include <hip/hip_runtime.h>

// LocallyConnected2D: B=16, H=W=64, CIN=32, 3x3 valid conv per-location weights,
// F=64, OR=OC=62. out[b,or,oc,f] = bias[or,oc,f] +
//   sum_{i,j,c} x[b,or+i,oc+j,c] * kernel[p, (i*3+j)*32+c, f],  p = or*62+oc.
//
// HBM-bound: kernel weights are 283 MB read exactly once. One block per p;
// stage the 16 batches' patches in LDS, stream weights from global.

#define NB 16       // batch
#define Hh 64
#define Ww 64
#define CIN 32
#define F 64
#define OR 62
#define OC 62
#define KK 288      // 3*3*32
#define PADK 292    // +4 dwords: breaks same-bank aliasing of stride-288 rows

__device__ __forceinline__ void fma4(float4& acc, float s, const float4 w) {
    acc.x = fmaf(s, w.x, acc.x);
    acc.y = fmaf(s, w.y, acc.y);
    acc.z = fmaf(s, w.z, acc.z);
    acc.w = fmaf(s, w.w, acc.w);
}

__global__ __launch_bounds__(256)
void lc2d_kernel(const float* __restrict__ x,
                 const float* __restrict__ kern,
                 const float* __restrict__ bias,
                 float* __restrict__ out) {
    __shared__ float patch[NB * PADK];   // 16*292*4 B = 18688 B

    const int p   = blockIdx.x;          // 0..3843
    const int orr = p / OC;
    const int occ = p - orr * OC;
    const int tid = threadIdx.x;

    // ---- stage patches: 16 batches x 288 k-values, as float4 (coalesced) ----
    // k = i*96 + j*32 + c  (keras extract_image_patches order: kh, kw, cin)
    for (int idx = tid; idx < (NB * KK) / 4; idx += 256) {
        const int e = idx << 2;              // element index, multiple of 4
        const int b = e / KK;
        const int k = e - b * KK;
        const int i = k / 96;
        const int rem = k - i * 96;
        const int j = rem >> 5;              // /32
        const int c = rem & 31;
        const float4 v = *reinterpret_cast<const float4*>(
            x + (((b * Hh + orr + i) * Ww) + (occ + j)) * CIN + c);
        *reinterpret_cast<float4*>(&patch[b * PADK + k]) = v;
    }
    __syncthreads();

    // ---- compute: thread = (b = tid/16, f4 = 4*(tid%16)) -> 4 outputs ----
    const int fgrp = tid & 15;
    const int b    = tid >> 4;
    const int f0   = fgrp << 2;

    float4 acc = *reinterpret_cast<const float4*>(bias + p * F + f0);

    const float* __restrict__ wp = kern + (size_t)p * (KK * F) + f0;
    const float* __restrict__ pp = &patch[b * PADK];

#pragma unroll 2
    for (int k0 = 0; k0 < KK; k0 += 4) {
        const float4 pk = *reinterpret_cast<const float4*>(pp + k0);
        const float4 w0 = *reinterpret_cast<const float4*>(wp + (k0 + 0) * F);
        const float4 w1 = *reinterpret_cast<const float4*>(wp + (k0 + 1) * F);
        const float4 w2 = *reinterpret_cast<const float4*>(wp + (k0 + 2) * F);
        const float4 w3 = *reinterpret_cast<const float4*>(wp + (k0 + 3) * F);
        fma4(acc, pk.x, w0);
        fma4(acc, pk.y, w1);
        fma4(acc, pk.z, w2);
        fma4(acc, pk.w, w3);
    }

    // out[b, orr, occ, f0..f0+3]
    float* op = out + (((size_t)b * OR + orr) * OC + occ) * F + f0;
    *reinterpret_cast<float4*>(op) = acc;
}

extern "C" void kernel_launch(void* const* d_in, const int* in_sizes, int n_in,
                              void* d_out, int out_size, void* d_ws, size_t ws_size,
                              hipStream_t stream) {
    const float* x    = (const float*)d_in[0];
    const float* kern = (const float*)d_in[1];
    const float* bias = (const float*)d_in[2];
    float* out = (float*)d_out;
    dim3 grid(OR * OC);
    dim3 block(256);
    lc2d_kernel<<<grid, block, 0, stream>>>(x, kern, bias, out);
}